// Round 8
// baseline (434.408 us; speedup 1.0000x reference)
//
#include <hip/hip_runtime.h>
#include <hip/hip_bf16.h>

// GCN: h = (0.5A)^2 x ; h = relu(h W1 + b1) ; h = (0.5A)^2 h ; h = h W2 + b2
// Rewrites:
//  - (0.5A)^2 (relu(...)) W2 + b2 == (0.5A)^2 (relu(...) W2) + b2
//  - SpMMs via on-device CSR, gather-side, zero float atomics
//  - dense layer: row-per-lane (wave-uniform W reads)
//  - CSR build history:
//    r3 direct scatter: partial-line-writeback bound (100 MB WRITE / 12.8 MB)
//    r4 bucket=128: atomic-line contention (375 us)
//    r5 bucket=8+padding: cross-XCD partial-line WB (95 MB)
//    r6 2-pass radix, single-writer lines: 377 us total
//    r7/r8: build with ZERO global atomics + no memset:
//       K1 per-block region hist -> partial[block][256] (single-writer rows)
//       K2 one block: col-sum partials, LDS scan -> region_off; rewrite
//          partial[b][t] in place as per-(block,region) scatter bases
//       K3 scatter via LDS rank only; K4 region sort (unchanged)
//       spmm: nontemporal cv loads, XCD-contiguous block swizzle,
//       bias as template param, nontemporal final store (via native clang
//       vector type — HIP float4 is a class, builtin rejects it; r7 compile fail).
// Buffer plan (ping-pong, d_out used as scratch; stg overlays B):
//  s1 spmm32: x -> d_out ; s2 spmm32: d_out -> B ; s3 dense: B -> d_out
//  s4 spmm64: d_out -> B ; s5 spmm64: B -> d_out (+b2)

#define REGION_SHIFT 9               // 512 rows per region
#define REGION_SIZE  (1 << REGION_SHIFT)
#define COL_MASK 0x1FFFF             // 17 bits, N=100000 < 131072
#define GBUILD 256                   // blocks for K1/K3 (chunking must match!)

typedef float nat_float4 __attribute__((ext_vector_type(4)));

// each XCD gets a contiguous block range (assumes round-robin bid%8 -> XCD;
// if mapping differs this only affects locality, not correctness)
__device__ inline int swizzle_bid(int b, int nb) {
    int per = nb >> 3;
    int xcd = b & 7, sb = b >> 3;
    return (sb < per) ? (xcd * per + sb) : b;
}

// ---- K1: per-block LDS region hist -> partial[block][256] ----
__global__ void region_count_kernel(const int* __restrict__ er, int E,
                                    int* __restrict__ partial) {
    __shared__ int hist[256];
    int t = threadIdx.x;
    hist[t] = 0;
    __syncthreads();
    int chunk = (E + gridDim.x - 1) / gridDim.x;
    int s = blockIdx.x * chunk;
    int e = min(E, s + chunk);
    for (int i = s + t; i < e; i += 256)
        atomicAdd(&hist[er[i] >> REGION_SHIFT], 1);
    __syncthreads();
    partial[blockIdx.x * 256 + t] = hist[t];   // single-writer 1KB row
}

// ---- K2: one block. totals -> scan -> region_off; rewrite partial in place
// as per-(block,region) bases. Column access over partial is coalesced.
__global__ void region_scan_kernel(int* __restrict__ partial,
                                   int* __restrict__ region_off,
                                   int nreg, int E, int G) {
    __shared__ int s[256];
    int t = threadIdx.x;
    int total = 0;
    if (t < nreg)
        for (int b = 0; b < G; b++) total += partial[b * 256 + t];
    s[t] = (t < nreg) ? total : 0;
    __syncthreads();
    for (int off = 1; off < 256; off <<= 1) {
        int x = (t >= off) ? s[t - off] : 0;
        __syncthreads();
        s[t] += x;
        __syncthreads();
    }
    if (t < nreg) {
        int run = s[t] - total;        // exclusive prefix = region start
        region_off[t] = run;
        for (int b = 0; b < G; b++) {
            int c = partial[b * 256 + t];
            partial[b * 256 + t] = run;
            run += c;
        }
    }
    if (t == 0) region_off[nreg] = E;
}

// ---- K3: coarse scatter, LDS rank only (no global atomics) ----
__global__ void coarse_scatter_kernel(const int* __restrict__ er,
                                      const int* __restrict__ ec,
                                      const float* __restrict__ ev, int E,
                                      const int* __restrict__ partial,
                                      int2* __restrict__ stg) {
    __shared__ int cnt2[256], gbase[256];
    int t = threadIdx.x;
    cnt2[t] = 0;
    gbase[t] = partial[blockIdx.x * 256 + t];
    __syncthreads();
    int chunk = (E + gridDim.x - 1) / gridDim.x;   // identical to K1
    int s0 = blockIdx.x * chunk;
    int e0 = min(E, s0 + chunk);
    for (int i = s0 + t; i < e0; i += 256) {
        int r = er[i];
        int b = r >> REGION_SHIFT;
        int rank = atomicAdd(&cnt2[b], 1);
        int2 rec;
        rec.x = ec[i] | ((r & (REGION_SIZE - 1)) << 17);
        rec.y = __float_as_int(0.5f * ev[i]);
        stg[gbase[b] + rank] = rec;                // block-private run
    }
}

// ---- K4: per-region LDS sort -> row_ptr + cv ----
__global__ void region_sort_kernel(const int2* __restrict__ stg,
                                   const int* __restrict__ region_off,
                                   int* __restrict__ row_ptr,
                                   int2* __restrict__ cv, int N, int E) {
    __shared__ int hist[REGION_SIZE];
    __shared__ int wp_local[REGION_SIZE];
    __shared__ int psum[256];
    int cb = blockIdx.x;
    int lo = cb << REGION_SHIFT;
    if (lo >= N) return;
    int hi = min(lo + REGION_SIZE, N);
    int cnt = hi - lo;
    int t = threadIdx.x;
    for (int r = t; r < cnt; r += 256) hist[r] = 0;
    __syncthreads();
    int start = region_off[cb];
    int end   = region_off[cb + 1];
    for (int q = start + t; q < end; q += 256)
        atomicAdd(&hist[stg[q].x >> 17], 1);
    __syncthreads();
    int a0 = (2 * t     < cnt) ? hist[2 * t]     : 0;
    int a1 = (2 * t + 1 < cnt) ? hist[2 * t + 1] : 0;
    psum[t] = a0 + a1;
    __syncthreads();
    for (int off = 1; off < 256; off <<= 1) {
        int x = (t >= off) ? psum[t - off] : 0;
        __syncthreads();
        psum[t] += x;
        __syncthreads();
    }
    int excl = psum[t] - (a0 + a1);
    if (2 * t < cnt) {
        wp_local[2 * t] = start + excl;
        row_ptr[lo + 2 * t] = start + excl;
    }
    if (2 * t + 1 < cnt) {
        wp_local[2 * t + 1] = start + excl + a0;
        row_ptr[lo + 2 * t + 1] = start + excl + a0;
    }
    if (cb == 0 && t == 0) row_ptr[N] = E;
    __syncthreads();
    for (int q = start + t; q < end; q += 256) {
        int2 e = stg[q];
        int lr = e.x >> 17;
        int p = atomicAdd(&wp_local[lr], 1);      // LDS atomic
        int2 o;
        o.x = e.x & COL_MASK;
        o.y = e.y;
        cv[p] = o;                                 // private 64KB window
    }
}

// ---------------- CSR SpMM, gather-side ----------------
template <int D, bool FINAL>
__global__ __launch_bounds__(256) void spmm_csr_kernel(
        const float* __restrict__ h,
        const int* __restrict__ row_ptr,
        const int2* __restrict__ cv,
        float* __restrict__ out,
        const float* __restrict__ bias,  // used iff FINAL
        int N) {
    constexpr int LPR = D / 4;
    int bid = swizzle_bid(blockIdx.x, gridDim.x);
    int gid = bid * blockDim.x + threadIdx.x;
    int row = gid / LPR;
    int sub = gid % LPR;
    if (row >= N) return;
    int start = row_ptr[row];
    int end   = row_ptr[row + 1];
    const long long* cvq = (const long long*)cv;   // 8B packed (col, val)
    float4 acc = make_float4(0.f, 0.f, 0.f, 0.f);
    int j = start;
    for (; j + 4 <= end; j += 4) {
        long long q0 = __builtin_nontemporal_load(cvq + j);
        long long q1 = __builtin_nontemporal_load(cvq + j + 1);
        long long q2 = __builtin_nontemporal_load(cvq + j + 2);
        long long q3 = __builtin_nontemporal_load(cvq + j + 3);
        int c0 = (int)q0, c1 = (int)q1, c2 = (int)q2, c3 = (int)q3;
        float4 h0 = reinterpret_cast<const float4*>(h + (long long)c0 * D)[sub];
        float4 h1 = reinterpret_cast<const float4*>(h + (long long)c1 * D)[sub];
        float4 h2 = reinterpret_cast<const float4*>(h + (long long)c2 * D)[sub];
        float4 h3 = reinterpret_cast<const float4*>(h + (long long)c3 * D)[sub];
        float v0 = __int_as_float((int)(q0 >> 32));
        float v1 = __int_as_float((int)(q1 >> 32));
        float v2 = __int_as_float((int)(q2 >> 32));
        float v3 = __int_as_float((int)(q3 >> 32));
        acc.x = fmaf(v0, h0.x, acc.x); acc.y = fmaf(v0, h0.y, acc.y);
        acc.z = fmaf(v0, h0.z, acc.z); acc.w = fmaf(v0, h0.w, acc.w);
        acc.x = fmaf(v1, h1.x, acc.x); acc.y = fmaf(v1, h1.y, acc.y);
        acc.z = fmaf(v1, h1.z, acc.z); acc.w = fmaf(v1, h1.w, acc.w);
        acc.x = fmaf(v2, h2.x, acc.x); acc.y = fmaf(v2, h2.y, acc.y);
        acc.z = fmaf(v2, h2.z, acc.z); acc.w = fmaf(v2, h2.w, acc.w);
        acc.x = fmaf(v3, h3.x, acc.x); acc.y = fmaf(v3, h3.y, acc.y);
        acc.z = fmaf(v3, h3.z, acc.z); acc.w = fmaf(v3, h3.w, acc.w);
    }
    for (; j < end; j++) {
        long long q = __builtin_nontemporal_load(cvq + j);
        int c = (int)q;
        float v = __int_as_float((int)(q >> 32));
        float4 hv = reinterpret_cast<const float4*>(h + (long long)c * D)[sub];
        acc.x = fmaf(v, hv.x, acc.x); acc.y = fmaf(v, hv.y, acc.y);
        acc.z = fmaf(v, hv.z, acc.z); acc.w = fmaf(v, hv.w, acc.w);
    }
    if (FINAL) {
        acc.x += bias[sub * 4 + 0];
        acc.y += bias[sub * 4 + 1];
        acc.z += bias[sub * 4 + 2];
        acc.w += bias[sub * 4 + 3];
        nat_float4 nv = { acc.x, acc.y, acc.z, acc.w };
        __builtin_nontemporal_store(nv,
            reinterpret_cast<nat_float4*>(out + (long long)row * D) + sub);
    } else {
        reinterpret_cast<float4*>(out + (long long)row * D)[sub] = acc;
    }
}

// ---------------- fused dense: out = relu(h@W1 + b1) @ W2, row-per-lane ------
__global__ __launch_bounds__(256) void dense_fused_kernel(
        const float* __restrict__ h,   // [N,32]
        const float* __restrict__ W1,  // [32,64]
        const float* __restrict__ b1,  // [64]
        const float* __restrict__ W2,  // [64,64]
        float* __restrict__ out, int N) {
    __shared__ float buf[4 * 64 * 64];  // 64 KB: per-wave 4096-float tile
    int tid = threadIdx.x;
    int lane = tid & 63;
    int wave = tid >> 6;
    float* wbuf = &buf[wave * 4096];

    int rowbase = blockIdx.x * 256 + wave * 64;
    if (rowbase >= N) return;           // wave-uniform
    int row = rowbase + lane;
    bool valid = row < N;

    {   // cooperative, coalesced h stage: 64 rows x 32 floats contiguous
        const float* src = h + (long long)rowbase * 32;
        int maxf = (N - rowbase) * 32;
#pragma unroll
        for (int i = 0; i < 8; i++) {
            int f = i * 256 + lane * 4;
            int fc = (f + 4 <= maxf) ? f : (maxf >= 4 ? maxf - 4 : 0);
            float4 a = reinterpret_cast<const float4*>(src + fc)[0];
            int r = fc >> 5, k = fc & 31;
            float* dst = wbuf + r * 33 + k;
            dst[0] = a.x; dst[1] = a.y; dst[2] = a.z; dst[3] = a.w;
        }
    }

    float u[64];
#pragma unroll
    for (int j = 0; j < 64; j++) u[j] = b1[j];
    for (int k = 0; k < 32; k++) {
        float hk = wbuf[lane * 33 + k];
        const float* w1r = W1 + k * 64;
#pragma unroll
        for (int j = 0; j < 64; j++) u[j] = fmaf(hk, w1r[j], u[j]);
    }
#pragma unroll
    for (int j = 0; j < 64; j++) u[j] = fmaxf(u[j], 0.0f);

#pragma unroll
    for (int j = 0; j < 64; j++) wbuf[lane * 64 + ((j + lane) & 63)] = u[j];

    float v[64];
#pragma unroll
    for (int j = 0; j < 64; j++) v[j] = 0.0f;
    for (int k = 0; k < 64; k++) {
        float uk = wbuf[lane * 64 + ((k + lane) & 63)];
        const float* w2r = W2 + k * 64;
#pragma unroll
        for (int j = 0; j < 64; j++) v[j] = fmaf(uk, w2r[j], v[j]);
    }

    if (valid) {
        float4* op = reinterpret_cast<float4*>(out + (long long)row * 64);
#pragma unroll
        for (int m = 0; m < 16; m++) {
            float4 o;
            o.x = v[m * 4 + 0]; o.y = v[m * 4 + 1];
            o.z = v[m * 4 + 2]; o.w = v[m * 4 + 3];
            op[m] = o;
        }
    }
}

extern "C" void kernel_launch(void* const* d_in, const int* in_sizes, int n_in,
                              void* d_out, int out_size, void* d_ws, size_t ws_size,
                              hipStream_t stream) {
    const float* x        = (const float*)d_in[0];
    const float* edge_val = (const float*)d_in[1];
    const int*   edge_row = (const int*)d_in[2];
    const int*   edge_col = (const int*)d_in[3];
    const float* W1       = (const float*)d_in[4];
    const float* b1       = (const float*)d_in[5];
    const float* W2       = (const float*)d_in[6];
    const float* b2       = (const float*)d_in[7];
    float* out = (float*)d_out;

    const int N = in_sizes[0] / 32;   // 100000
    const int E = in_sizes[1];        // 1600000
    const int NREG = (N + REGION_SIZE - 1) >> REGION_SHIFT;  // 196

    // ws layout (stg overlays B: stg dead before B is first written)
    float* B          = (float*)d_ws;                 // N*64 floats (ping buffer)
    int2*  stg        = (int2*)d_ws;                  // E int2 (12.8 MB <= 25.6 MB)
    int*   row_ptr    = (int*)(B + (size_t)N * 64);   // N+1
    int*   region_off = row_ptr + (N + 1);            // NREG+1
    int*   partial    = region_off + (NREG + 1);      // GBUILD*256 ints
    size_t cvOff = (size_t)((char*)(partial + GBUILD * 256) - (char*)d_ws);
    cvOff = (cvOff + 7) & ~(size_t)7;
    int2* cv = (int2*)((char*)d_ws + cvOff);          // E packed edges

    const int BLK = 256;

    // ---- CSR build (2-pass radix, zero global atomics, no memset) ----
    region_count_kernel<<<GBUILD, 256, 0, stream>>>(edge_row, E, partial);
    region_scan_kernel<<<1, 256, 0, stream>>>(partial, region_off, NREG, E, GBUILD);
    coarse_scatter_kernel<<<GBUILD, 256, 0, stream>>>(edge_row, edge_col, edge_val,
                                                      E, partial, stg);
    region_sort_kernel<<<NREG, 256, 0, stream>>>(stg, region_off, row_ptr, cv, N, E);

    // ---- pipeline ----
    int g32 = ((N * 8)  + BLK - 1) / BLK;   // D=32: 8 lanes/row
    int g64 = ((N * 16) + BLK - 1) / BLK;   // D=64: 16 lanes/row

    spmm_csr_kernel<32, false><<<g32, BLK, 0, stream>>>(x, row_ptr, cv, out, nullptr, N);
    spmm_csr_kernel<32, false><<<g32, BLK, 0, stream>>>(out, row_ptr, cv, B, nullptr, N);
    dense_fused_kernel<<<(N + 255) / 256, 256, 0, stream>>>(B, W1, b1, W2, out, N);
    spmm_csr_kernel<64, false><<<g64, BLK, 0, stream>>>(out, row_ptr, cv, B, nullptr, N);
    spmm_csr_kernel<64, true><<<g64, BLK, 0, stream>>>(B, row_ptr, cv, out, b2, N);
}

// Round 9
// 349.224 us; speedup vs baseline: 1.2439x; 1.2439x over previous
//
#include <hip/hip_runtime.h>
#include <hip/hip_bf16.h>

// GCN: h = (0.5A)^2 x ; h = relu(h W1 + b1) ; h = (0.5A)^2 h ; h = h W2 + b2
// Rewrites:
//  - (0.5A)^2 (relu(...)) W2 + b2 == (0.5A)^2 (relu(...) W2) + b2
//  - SpMMs via on-device CSR, gather-side, zero float atomics
//  - intermediates stored BF16 (RTN), accumulation fp32: halves the random
//    gather traffic (r8: spmm64 FETCH 200 MB ~ 8 XCD x 25.6 MB fp32 table;
//    bf16 table = 12.8 MB -> compulsory ~102 MB)
//  - r8 regressions reverted: nontemporal cv loads (+18 MB FETCH), XCD
//    swizzle (no-op for random cols), K2 serial base-rewrite loop (~25 us)
//    replaced by parallel K2a/K2b.
// Buffers (d_out used as raw scratch until final write):
//  xb  = d_out[0,6.4MB)      bf16 x          (s0 convert, s1 read)
//  t0b = d_out[6.4,12.8MB)   bf16 t0         (s1 write, s2 read)
//  t1b = ws[0,6.4MB)         bf16 t1         (s2 write, s3 read)
//  t2b = d_out[12.8,25.6MB)  bf16 t2         (s3 write, s4 read)
//  t3b = ws[0,12.8MB)        bf16 t3         (s4 write, s5 read)
//  s5: out = spmm64(t3b) + b2 -> d_out fp32 (overwrites scratch)
//  stg overlays ws[0,12.8MB) during build (dead before s2).

#define REGION_SHIFT 9               // 512 rows per region
#define REGION_SIZE  (1 << REGION_SHIFT)
#define COL_MASK 0x1FFFF             // 17 bits, N=100000 < 131072
#define GBUILD 256                   // blocks for K1/K3 (chunking must match!)

typedef unsigned short u16;
typedef unsigned int   u32;

__device__ inline float bflo(u32 w) { return __uint_as_float(w << 16); }
__device__ inline float bfhi(u32 w) { return __uint_as_float(w & 0xffff0000u); }
// pack two fp32 -> bf16 pair (RTN-even), a in low half
__device__ inline u32 bfpack(float a, float b) {
    u32 ua = __float_as_uint(a), ub = __float_as_uint(b);
    ua = (ua + 0x7fffu + ((ua >> 16) & 1u)) >> 16;
    ub = (ub + 0x7fffu + ((ub >> 16) & 1u)) & 0xffff0000u;
    return ua | ub;
}

// ---- s0: fp32 -> bf16 convert (x table) ----
__global__ void f32_to_bf16_kernel(const float* __restrict__ in,
                                   u16* __restrict__ outb, int n4) {
    int i = blockIdx.x * blockDim.x + threadIdx.x;
    if (i >= n4) return;
    float4 a = reinterpret_cast<const float4*>(in)[i];
    uint2 o;
    o.x = bfpack(a.x, a.y);
    o.y = bfpack(a.z, a.w);
    reinterpret_cast<uint2*>(outb)[i] = o;
}

// ---- K1: per-block LDS region hist -> partial[block][256] ----
__global__ void region_count_kernel(const int* __restrict__ er, int E,
                                    int* __restrict__ partial) {
    __shared__ int hist[256];
    int t = threadIdx.x;
    hist[t] = 0;
    __syncthreads();
    int chunk = (E + gridDim.x - 1) / gridDim.x;
    int s = blockIdx.x * chunk;
    int e = min(E, s + chunk);
    for (int i = s + t; i < e; i += 256)
        atomicAdd(&hist[er[i] >> REGION_SHIFT], 1);
    __syncthreads();
    partial[blockIdx.x * 256 + t] = hist[t];   // single-writer 1KB row
}

// ---- K2a: one block: region totals -> exclusive scan -> region_off ----
__global__ void region_scan_kernel(const int* __restrict__ partial,
                                   int* __restrict__ region_off,
                                   int nreg, int E, int G) {
    __shared__ int s[256];
    int t = threadIdx.x;
    int total = 0;
    if (t < nreg)
        for (int b = 0; b < G; b++) total += partial[b * 256 + t];  // coalesced
    s[t] = (t < nreg) ? total : 0;
    __syncthreads();
    for (int off = 1; off < 256; off <<= 1) {
        int x = (t >= off) ? s[t - off] : 0;
        __syncthreads();
        s[t] += x;
        __syncthreads();
    }
    if (t < nreg) region_off[t] = s[t] - total;
    if (t == 0) region_off[nreg] = E;
}

// ---- K2b: per-region parallel scan over blocks: partial -> scatter bases ----
__global__ void region_base_kernel(int* __restrict__ partial,
                                   const int* __restrict__ region_off, int nreg) {
    __shared__ int s[256];
    int r = blockIdx.x;
    if (r >= nreg) return;
    int t = threadIdx.x;
    int c = partial[t * 256 + r];    // block t's count for region r
    s[t] = c;
    __syncthreads();
    for (int off = 1; off < 256; off <<= 1) {
        int x = (t >= off) ? s[t - off] : 0;
        __syncthreads();
        s[t] += x;
        __syncthreads();
    }
    partial[t * 256 + r] = region_off[r] + s[t] - c;   // exclusive base
}

// ---- K3: coarse scatter, LDS rank only (no global atomics) ----
__global__ void coarse_scatter_kernel(const int* __restrict__ er,
                                      const int* __restrict__ ec,
                                      const float* __restrict__ ev, int E,
                                      const int* __restrict__ partial,
                                      int2* __restrict__ stg) {
    __shared__ int cnt2[256], gbase[256];
    int t = threadIdx.x;
    cnt2[t] = 0;
    gbase[t] = partial[blockIdx.x * 256 + t];
    __syncthreads();
    int chunk = (E + gridDim.x - 1) / gridDim.x;   // identical to K1
    int s0 = blockIdx.x * chunk;
    int e0 = min(E, s0 + chunk);
    for (int i = s0 + t; i < e0; i += 256) {
        int r = er[i];
        int b = r >> REGION_SHIFT;
        int rank = atomicAdd(&cnt2[b], 1);
        int2 rec;
        rec.x = ec[i] | ((r & (REGION_SIZE - 1)) << 17);
        rec.y = __float_as_int(0.5f * ev[i]);
        stg[gbase[b] + rank] = rec;                // block-private run
    }
}

// ---- K4: per-region LDS sort -> row_ptr + cv ----
__global__ void region_sort_kernel(const int2* __restrict__ stg,
                                   const int* __restrict__ region_off,
                                   int* __restrict__ row_ptr,
                                   int2* __restrict__ cv, int N, int E) {
    __shared__ int hist[REGION_SIZE];
    __shared__ int wp_local[REGION_SIZE];
    __shared__ int psum[256];
    int cb = blockIdx.x;
    int lo = cb << REGION_SHIFT;
    if (lo >= N) return;
    int hi = min(lo + REGION_SIZE, N);
    int cnt = hi - lo;
    int t = threadIdx.x;
    for (int r = t; r < cnt; r += 256) hist[r] = 0;
    __syncthreads();
    int start = region_off[cb];
    int end   = region_off[cb + 1];
    for (int q = start + t; q < end; q += 256)
        atomicAdd(&hist[stg[q].x >> 17], 1);
    __syncthreads();
    int a0 = (2 * t     < cnt) ? hist[2 * t]     : 0;
    int a1 = (2 * t + 1 < cnt) ? hist[2 * t + 1] : 0;
    psum[t] = a0 + a1;
    __syncthreads();
    for (int off = 1; off < 256; off <<= 1) {
        int x = (t >= off) ? psum[t - off] : 0;
        __syncthreads();
        psum[t] += x;
        __syncthreads();
    }
    int excl = psum[t] - (a0 + a1);
    if (2 * t < cnt) {
        wp_local[2 * t] = start + excl;
        row_ptr[lo + 2 * t] = start + excl;
    }
    if (2 * t + 1 < cnt) {
        wp_local[2 * t + 1] = start + excl + a0;
        row_ptr[lo + 2 * t + 1] = start + excl + a0;
    }
    if (cb == 0 && t == 0) row_ptr[N] = E;
    __syncthreads();
    for (int q = start + t; q < end; q += 256) {
        int2 e = stg[q];
        int lr = e.x >> 17;
        int p = atomicAdd(&wp_local[lr], 1);      // LDS atomic
        int2 o;
        o.x = e.x & COL_MASK;
        o.y = e.y;
        cv[p] = o;                                 // private 64KB window
    }
}

// ---------------- CSR SpMM, gather-side, bf16 table / fp32 accum ------------
__device__ inline void fma8(float acc[8], float v, uint4 w) {
    acc[0] = fmaf(v, bflo(w.x), acc[0]); acc[1] = fmaf(v, bfhi(w.x), acc[1]);
    acc[2] = fmaf(v, bflo(w.y), acc[2]); acc[3] = fmaf(v, bfhi(w.y), acc[3]);
    acc[4] = fmaf(v, bflo(w.z), acc[4]); acc[5] = fmaf(v, bfhi(w.z), acc[5]);
    acc[6] = fmaf(v, bflo(w.w), acc[6]); acc[7] = fmaf(v, bfhi(w.w), acc[7]);
}

// D features/row; 8 features (16B) per lane; LPR = D/8 lanes per row.
// FINAL: add bias, write fp32 to out. else: write bf16.
template <int D, bool FINAL>
__global__ __launch_bounds__(256) void spmm_bf16_kernel(
        const u16* __restrict__ h,
        const int* __restrict__ row_ptr,
        const int2* __restrict__ cv,
        void* __restrict__ outp,
        const float* __restrict__ bias,  // used iff FINAL
        int N) {
    constexpr int LPR = D / 8;
    int gid = blockIdx.x * 256 + threadIdx.x;
    int row = gid / LPR;
    int sub = gid % LPR;
    if (row >= N) return;
    int start = row_ptr[row];
    int end   = row_ptr[row + 1];
    const long long* cvq = (const long long*)cv;
    float acc[8] = {0.f, 0.f, 0.f, 0.f, 0.f, 0.f, 0.f, 0.f};
    int j = start;
    for (; j + 4 <= end; j += 4) {
        long long q0 = cvq[j],     q1 = cvq[j + 1];
        long long q2 = cvq[j + 2], q3 = cvq[j + 3];
        uint4 w0 = reinterpret_cast<const uint4*>(h + (size_t)(int)q0 * D)[sub];
        uint4 w1 = reinterpret_cast<const uint4*>(h + (size_t)(int)q1 * D)[sub];
        uint4 w2 = reinterpret_cast<const uint4*>(h + (size_t)(int)q2 * D)[sub];
        uint4 w3 = reinterpret_cast<const uint4*>(h + (size_t)(int)q3 * D)[sub];
        fma8(acc, __int_as_float((int)(q0 >> 32)), w0);
        fma8(acc, __int_as_float((int)(q1 >> 32)), w1);
        fma8(acc, __int_as_float((int)(q2 >> 32)), w2);
        fma8(acc, __int_as_float((int)(q3 >> 32)), w3);
    }
    for (; j < end; j++) {
        long long q = cvq[j];
        uint4 w = reinterpret_cast<const uint4*>(h + (size_t)(int)q * D)[sub];
        fma8(acc, __int_as_float((int)(q >> 32)), w);
    }
    if (FINAL) {
        float* op = (float*)outp + (size_t)row * 64 + sub * 8;
#pragma unroll
        for (int k = 0; k < 8; k++) acc[k] += bias[sub * 8 + k];
        float4 o0 = make_float4(acc[0], acc[1], acc[2], acc[3]);
        float4 o1 = make_float4(acc[4], acc[5], acc[6], acc[7]);
        reinterpret_cast<float4*>(op)[0] = o0;
        reinterpret_cast<float4*>(op)[1] = o1;
    } else {
        u16* ob = (u16*)outp + (size_t)row * D + sub * 8;
        uint4 o;
        o.x = bfpack(acc[0], acc[1]);
        o.y = bfpack(acc[2], acc[3]);
        o.z = bfpack(acc[4], acc[5]);
        o.w = bfpack(acc[6], acc[7]);
        reinterpret_cast<uint4*>(ob)[0] = o;
    }
}

// ------- fused dense: t2 = relu(t1@W1 + b1) @ W2, bf16 in/out, row-per-lane --
__global__ __launch_bounds__(256) void dense_fused_kernel(
        const u16* __restrict__ h,     // [N,32] bf16
        const float* __restrict__ W1,  // [32,64]
        const float* __restrict__ b1,  // [64]
        const float* __restrict__ W2,  // [64,64]
        u16* __restrict__ outb, int N) {
    __shared__ float buf[4 * 64 * 64];  // 64 KB: per-wave 4096-float tile
    int tid = threadIdx.x;
    int lane = tid & 63;
    int wave = tid >> 6;
    float* wbuf = &buf[wave * 4096];

    int rowbase = blockIdx.x * 256 + wave * 64;
    if (rowbase >= N) return;           // wave-uniform
    int row = rowbase + lane;
    bool valid = row < N;

    {   // cooperative, coalesced h stage: 64 rows x 32 bf16, cvt to fp32 LDS
        const u16* src = h + (size_t)rowbase * 32;
        int maxf = (N - rowbase) * 32;  // valid bf16 elems in this wave's span
#pragma unroll
        for (int i = 0; i < 8; i++) {
            int f = i * 256 + lane * 4;
            int fc = (f + 4 <= maxf) ? f : (maxf >= 4 ? maxf - 4 : 0);
            uint2 d = reinterpret_cast<const uint2*>(src + fc)[0];
            int r = fc >> 5, k = fc & 31;
            float* dst = wbuf + r * 33 + k;
            dst[0] = bflo(d.x); dst[1] = bfhi(d.x);
            dst[2] = bflo(d.y); dst[3] = bfhi(d.y);
        }
    }

    float u[64];
#pragma unroll
    for (int j = 0; j < 64; j++) u[j] = b1[j];
    for (int k = 0; k < 32; k++) {
        float hk = wbuf[lane * 33 + k];
        const float* w1r = W1 + k * 64;
#pragma unroll
        for (int j = 0; j < 64; j++) u[j] = fmaf(hk, w1r[j], u[j]);
    }
#pragma unroll
    for (int j = 0; j < 64; j++) u[j] = fmaxf(u[j], 0.0f);

#pragma unroll
    for (int j = 0; j < 64; j++) wbuf[lane * 64 + ((j + lane) & 63)] = u[j];

    float v[64];
#pragma unroll
    for (int j = 0; j < 64; j++) v[j] = 0.0f;
    for (int k = 0; k < 64; k++) {
        float uk = wbuf[lane * 64 + ((k + lane) & 63)];
        const float* w2r = W2 + k * 64;
#pragma unroll
        for (int j = 0; j < 64; j++) v[j] = fmaf(uk, w2r[j], v[j]);
    }

    if (valid) {
        uint4* op = reinterpret_cast<uint4*>(outb + (size_t)row * 64);
#pragma unroll
        for (int m = 0; m < 8; m++) {
            uint4 o;
            o.x = bfpack(v[m * 8 + 0], v[m * 8 + 1]);
            o.y = bfpack(v[m * 8 + 2], v[m * 8 + 3]);
            o.z = bfpack(v[m * 8 + 4], v[m * 8 + 5]);
            o.w = bfpack(v[m * 8 + 6], v[m * 8 + 7]);
            op[m] = o;
        }
    }
}

extern "C" void kernel_launch(void* const* d_in, const int* in_sizes, int n_in,
                              void* d_out, int out_size, void* d_ws, size_t ws_size,
                              hipStream_t stream) {
    const float* x        = (const float*)d_in[0];
    const float* edge_val = (const float*)d_in[1];
    const int*   edge_row = (const int*)d_in[2];
    const int*   edge_col = (const int*)d_in[3];
    const float* W1       = (const float*)d_in[4];
    const float* b1       = (const float*)d_in[5];
    const float* W2       = (const float*)d_in[6];
    const float* b2       = (const float*)d_in[7];
    float* out = (float*)d_out;

    const int N = in_sizes[0] / 32;   // 100000
    const int E = in_sizes[1];        // 1600000
    const int NREG = (N + REGION_SIZE - 1) >> REGION_SHIFT;  // 196

    // --- d_out as raw scratch (fp32 final write overwrites all) ---
    u16* xb  = (u16*)d_out;                    // N*32 bf16
    u16* t0b = xb + (size_t)N * 32;            // N*32 bf16
    u16* t2b = (u16*)d_out + (size_t)N * 64;   // N*64 bf16 (bytes [12.8,25.6MB))

    // --- ws layout ---
    u16*  wsb = (u16*)d_ws;                    // N*64 bf16: t1b then t3b
    int2* stg = (int2*)d_ws;                   // E int2 overlay (build only)
    int*  row_ptr    = (int*)((char*)d_ws + (size_t)N * 64 * 2);  // N+1
    int*  region_off = row_ptr + (N + 1);      // NREG+1
    int*  partial    = region_off + (NREG + 1);// GBUILD*256
    size_t cvOff = (size_t)((char*)(partial + GBUILD * 256) - (char*)d_ws);
    cvOff = (cvOff + 7) & ~(size_t)7;
    int2* cv = (int2*)((char*)d_ws + cvOff);   // E packed edges
    u16* t1b = wsb;
    u16* t3b = wsb;

    // ---- CSR build (2-pass radix, zero global atomics, no memset) ----
    region_count_kernel<<<GBUILD, 256, 0, stream>>>(edge_row, E, partial);
    region_scan_kernel<<<1, 256, 0, stream>>>(partial, region_off, NREG, E, GBUILD);
    region_base_kernel<<<NREG, 256, 0, stream>>>(partial, region_off, NREG);
    coarse_scatter_kernel<<<GBUILD, 256, 0, stream>>>(edge_row, edge_col, edge_val,
                                                      E, partial, stg);
    region_sort_kernel<<<NREG, 256, 0, stream>>>(stg, region_off, row_ptr, cv, N, E);

    // ---- pipeline ----
    int n4 = (N * 32) / 4;
    f32_to_bf16_kernel<<<(n4 + 255) / 256, 256, 0, stream>>>(x, xb, n4);

    int g32 = (N * 4 + 255) / 256;   // D=32: 4 lanes/row
    int g64 = (N * 8 + 255) / 256;   // D=64: 8 lanes/row

    spmm_bf16_kernel<32, false><<<g32, 256, 0, stream>>>(xb, row_ptr, cv, t0b, nullptr, N);
    spmm_bf16_kernel<32, false><<<g32, 256, 0, stream>>>(t0b, row_ptr, cv, t1b, nullptr, N);
    dense_fused_kernel<<<(N + 255) / 256, 256, 0, stream>>>(t1b, W1, b1, W2, t2b, N);
    spmm_bf16_kernel<64, false><<<g64, 256, 0, stream>>>(t2b, row_ptr, cv, t3b, nullptr, N);
    spmm_bf16_kernel<64, true><<<g64, 256, 0, stream>>>(t3b, row_ptr, cv, out, b2, N);
}

// Round 10
// 306.844 us; speedup vs baseline: 1.4157x; 1.1381x over previous
//
#include <hip/hip_runtime.h>
#include <hip/hip_bf16.h>

// GCN: h = (0.5A)^2 x ; h = relu(h W1 + b1) ; h = (0.5A)^2 h ; h = h W2 + b2
// Rewrites:
//  - (0.5A)^2 (relu(...)) W2 + b2 == (0.5A)^2 (relu(...) W2) + b2
//  - SpMMs via on-device CSR, gather-side, zero float atomics
//  - intermediates stored BF16 (RTN), accumulation fp32 (r9: halved gather
//    traffic, 434 -> 349 us)
//  - r10 (this): dense layer on MFMA (r9 dense was latency-bound fp32 vector:
//    58 us at 15% occupancy / 16% VALU). One wave per 16-row tile,
//    mfma_f32_16x16x32_bf16; W1/W2 as bf16 B-frags in registers; u goes
//    C-layout -> LDS -> A-layout; 12 MFMAs/tile; coalesced bf16 store.
// Buffers (d_out used as raw scratch until final write):
//  xb  = d_out[0,6.4MB)      bf16 x          (s0 convert, s1 read)
//  t0b = d_out[6.4,12.8MB)   bf16 t0         (s1 write, s2 read)
//  t1b = ws[0,6.4MB)         bf16 t1         (s2 write, s3 read)
//  t2b = d_out[12.8,25.6MB)  bf16 t2         (s3 write, s4 read)
//  t3b = ws[0,12.8MB)        bf16 t3         (s4 write, s5 read)
//  s5: out = spmm64(t3b) + b2 -> d_out fp32 (overwrites scratch)
//  stg overlays ws[0,12.8MB) during build (dead before s2).

#define REGION_SHIFT 9               // 512 rows per region
#define REGION_SIZE  (1 << REGION_SHIFT)
#define COL_MASK 0x1FFFF             // 17 bits, N=100000 < 131072
#define GBUILD 256                   // blocks for K1/K3 (chunking must match!)

typedef unsigned short u16;
typedef unsigned int   u32;
typedef __attribute__((ext_vector_type(8))) short bf16x8;
typedef __attribute__((ext_vector_type(4))) float f32x4;

__device__ inline float bflo(u32 w) { return __uint_as_float(w << 16); }
__device__ inline float bfhi(u32 w) { return __uint_as_float(w & 0xffff0000u); }
// pack two fp32 -> bf16 pair (RTN-even), a in low half
__device__ inline u32 bfpack(float a, float b) {
    u32 ua = __float_as_uint(a), ub = __float_as_uint(b);
    ua = (ua + 0x7fffu + ((ua >> 16) & 1u)) >> 16;
    ub = (ub + 0x7fffu + ((ub >> 16) & 1u)) & 0xffff0000u;
    return ua | ub;
}
__device__ inline u16 bf1(float f) {
    u32 u = __float_as_uint(f);
    return (u16)((u + 0x7fffu + ((u >> 16) & 1u)) >> 16);
}

// ---- s0: fp32 -> bf16 convert (x table) ----
__global__ void f32_to_bf16_kernel(const float* __restrict__ in,
                                   u16* __restrict__ outb, int n4) {
    int i = blockIdx.x * blockDim.x + threadIdx.x;
    if (i >= n4) return;
    float4 a = reinterpret_cast<const float4*>(in)[i];
    uint2 o;
    o.x = bfpack(a.x, a.y);
    o.y = bfpack(a.z, a.w);
    reinterpret_cast<uint2*>(outb)[i] = o;
}

// ---- K1: per-block LDS region hist -> partial[block][256] ----
__global__ void region_count_kernel(const int* __restrict__ er, int E,
                                    int* __restrict__ partial) {
    __shared__ int hist[256];
    int t = threadIdx.x;
    hist[t] = 0;
    __syncthreads();
    int chunk = (E + gridDim.x - 1) / gridDim.x;
    int s = blockIdx.x * chunk;
    int e = min(E, s + chunk);
    for (int i = s + t; i < e; i += 256)
        atomicAdd(&hist[er[i] >> REGION_SHIFT], 1);
    __syncthreads();
    partial[blockIdx.x * 256 + t] = hist[t];   // single-writer 1KB row
}

// ---- K2a: one block: region totals -> exclusive scan -> region_off ----
__global__ void region_scan_kernel(const int* __restrict__ partial,
                                   int* __restrict__ region_off,
                                   int nreg, int E, int G) {
    __shared__ int s[256];
    int t = threadIdx.x;
    int total = 0;
    if (t < nreg)
        for (int b = 0; b < G; b++) total += partial[b * 256 + t];  // coalesced
    s[t] = (t < nreg) ? total : 0;
    __syncthreads();
    for (int off = 1; off < 256; off <<= 1) {
        int x = (t >= off) ? s[t - off] : 0;
        __syncthreads();
        s[t] += x;
        __syncthreads();
    }
    if (t < nreg) region_off[t] = s[t] - total;
    if (t == 0) region_off[nreg] = E;
}

// ---- K2b: per-region parallel scan over blocks: partial -> scatter bases ----
__global__ void region_base_kernel(int* __restrict__ partial,
                                   const int* __restrict__ region_off, int nreg) {
    __shared__ int s[256];
    int r = blockIdx.x;
    if (r >= nreg) return;
    int t = threadIdx.x;
    int c = partial[t * 256 + r];    // block t's count for region r
    s[t] = c;
    __syncthreads();
    for (int off = 1; off < 256; off <<= 1) {
        int x = (t >= off) ? s[t - off] : 0;
        __syncthreads();
        s[t] += x;
        __syncthreads();
    }
    partial[t * 256 + r] = region_off[r] + s[t] - c;   // exclusive base
}

// ---- K3: coarse scatter, LDS rank only (no global atomics) ----
__global__ void coarse_scatter_kernel(const int* __restrict__ er,
                                      const int* __restrict__ ec,
                                      const float* __restrict__ ev, int E,
                                      const int* __restrict__ partial,
                                      int2* __restrict__ stg) {
    __shared__ int cnt2[256], gbase[256];
    int t = threadIdx.x;
    cnt2[t] = 0;
    gbase[t] = partial[blockIdx.x * 256 + t];
    __syncthreads();
    int chunk = (E + gridDim.x - 1) / gridDim.x;   // identical to K1
    int s0 = blockIdx.x * chunk;
    int e0 = min(E, s0 + chunk);
    for (int i = s0 + t; i < e0; i += 256) {
        int r = er[i];
        int b = r >> REGION_SHIFT;
        int rank = atomicAdd(&cnt2[b], 1);
        int2 rec;
        rec.x = ec[i] | ((r & (REGION_SIZE - 1)) << 17);
        rec.y = __float_as_int(0.5f * ev[i]);
        stg[gbase[b] + rank] = rec;                // block-private run
    }
}

// ---- K4: per-region LDS sort -> row_ptr + cv ----
__global__ void region_sort_kernel(const int2* __restrict__ stg,
                                   const int* __restrict__ region_off,
                                   int* __restrict__ row_ptr,
                                   int2* __restrict__ cv, int N, int E) {
    __shared__ int hist[REGION_SIZE];
    __shared__ int wp_local[REGION_SIZE];
    __shared__ int psum[256];
    int cb = blockIdx.x;
    int lo = cb << REGION_SHIFT;
    if (lo >= N) return;
    int hi = min(lo + REGION_SIZE, N);
    int cnt = hi - lo;
    int t = threadIdx.x;
    for (int r = t; r < cnt; r += 256) hist[r] = 0;
    __syncthreads();
    int start = region_off[cb];
    int end   = region_off[cb + 1];
    for (int q = start + t; q < end; q += 256)
        atomicAdd(&hist[stg[q].x >> 17], 1);
    __syncthreads();
    int a0 = (2 * t     < cnt) ? hist[2 * t]     : 0;
    int a1 = (2 * t + 1 < cnt) ? hist[2 * t + 1] : 0;
    psum[t] = a0 + a1;
    __syncthreads();
    for (int off = 1; off < 256; off <<= 1) {
        int x = (t >= off) ? psum[t - off] : 0;
        __syncthreads();
        psum[t] += x;
        __syncthreads();
    }
    int excl = psum[t] - (a0 + a1);
    if (2 * t < cnt) {
        wp_local[2 * t] = start + excl;
        row_ptr[lo + 2 * t] = start + excl;
    }
    if (2 * t + 1 < cnt) {
        wp_local[2 * t + 1] = start + excl + a0;
        row_ptr[lo + 2 * t + 1] = start + excl + a0;
    }
    if (cb == 0 && t == 0) row_ptr[N] = E;
    __syncthreads();
    for (int q = start + t; q < end; q += 256) {
        int2 e = stg[q];
        int lr = e.x >> 17;
        int p = atomicAdd(&wp_local[lr], 1);      // LDS atomic
        int2 o;
        o.x = e.x & COL_MASK;
        o.y = e.y;
        cv[p] = o;                                 // private 64KB window
    }
}

// ---------------- CSR SpMM, gather-side, bf16 table / fp32 accum ------------
__device__ inline void fma8(float acc[8], float v, uint4 w) {
    acc[0] = fmaf(v, bflo(w.x), acc[0]); acc[1] = fmaf(v, bfhi(w.x), acc[1]);
    acc[2] = fmaf(v, bflo(w.y), acc[2]); acc[3] = fmaf(v, bfhi(w.y), acc[3]);
    acc[4] = fmaf(v, bflo(w.z), acc[4]); acc[5] = fmaf(v, bfhi(w.z), acc[5]);
    acc[6] = fmaf(v, bflo(w.w), acc[6]); acc[7] = fmaf(v, bfhi(w.w), acc[7]);
}

// D features/row; 8 features (16B) per lane; LPR = D/8 lanes per row.
// FINAL: add bias, write fp32 to out. else: write bf16.
template <int D, bool FINAL>
__global__ __launch_bounds__(256) void spmm_bf16_kernel(
        const u16* __restrict__ h,
        const int* __restrict__ row_ptr,
        const int2* __restrict__ cv,
        void* __restrict__ outp,
        const float* __restrict__ bias,  // used iff FINAL
        int N) {
    constexpr int LPR = D / 8;
    int gid = blockIdx.x * 256 + threadIdx.x;
    int row = gid / LPR;
    int sub = gid % LPR;
    if (row >= N) return;
    int start = row_ptr[row];
    int end   = row_ptr[row + 1];
    const long long* cvq = (const long long*)cv;
    float acc[8] = {0.f, 0.f, 0.f, 0.f, 0.f, 0.f, 0.f, 0.f};
    int j = start;
    for (; j + 4 <= end; j += 4) {
        long long q0 = cvq[j],     q1 = cvq[j + 1];
        long long q2 = cvq[j + 2], q3 = cvq[j + 3];
        uint4 w0 = reinterpret_cast<const uint4*>(h + (size_t)(int)q0 * D)[sub];
        uint4 w1 = reinterpret_cast<const uint4*>(h + (size_t)(int)q1 * D)[sub];
        uint4 w2 = reinterpret_cast<const uint4*>(h + (size_t)(int)q2 * D)[sub];
        uint4 w3 = reinterpret_cast<const uint4*>(h + (size_t)(int)q3 * D)[sub];
        fma8(acc, __int_as_float((int)(q0 >> 32)), w0);
        fma8(acc, __int_as_float((int)(q1 >> 32)), w1);
        fma8(acc, __int_as_float((int)(q2 >> 32)), w2);
        fma8(acc, __int_as_float((int)(q3 >> 32)), w3);
    }
    for (; j < end; j++) {
        long long q = cvq[j];
        uint4 w = reinterpret_cast<const uint4*>(h + (size_t)(int)q * D)[sub];
        fma8(acc, __int_as_float((int)(q >> 32)), w);
    }
    if (FINAL) {
        float* op = (float*)outp + (size_t)row * 64 + sub * 8;
#pragma unroll
        for (int k = 0; k < 8; k++) acc[k] += bias[sub * 8 + k];
        float4 o0 = make_float4(acc[0], acc[1], acc[2], acc[3]);
        float4 o1 = make_float4(acc[4], acc[5], acc[6], acc[7]);
        reinterpret_cast<float4*>(op)[0] = o0;
        reinterpret_cast<float4*>(op)[1] = o1;
    } else {
        u16* ob = (u16*)outp + (size_t)row * D + sub * 8;
        uint4 o;
        o.x = bfpack(acc[0], acc[1]);
        o.y = bfpack(acc[2], acc[3]);
        o.z = bfpack(acc[4], acc[5]);
        o.w = bfpack(acc[6], acc[7]);
        reinterpret_cast<uint4*>(ob)[0] = o;
    }
}

// ------- MFMA dense: t2 = relu(t1@W1 + b1) @ W2, bf16 in/out ----------------
// One wave per 16-row tile. 16x16x32 bf16 MFMA.
// A frag: lane holds A[m=lane&15][k=quad*8+j]; B frag: B[k=quad*8+j][n=lane&15]
// C/D:    lane holds C[row=quad*4+i][col=lane&15]   (m89/m118/m120-verified)
__global__ __launch_bounds__(256) void dense_mfma_kernel(
        const u16* __restrict__ h,     // [N,32] bf16
        const float* __restrict__ W1,  // [32,64]
        const float* __restrict__ b1,  // [64]
        const float* __restrict__ W2,  // [64,64]
        u16* __restrict__ outb, int N) {
    __shared__ __align__(16) u16 tiles[4][16][80];  // per-wave tile, pad 80
    int tid = threadIdx.x;
    int lane = tid & 63;
    int wave = tid >> 6;
    int n16 = lane & 15;
    int quad = lane >> 4;
    u16 (*tile)[80] = tiles[wave];

    int tilebase = (blockIdx.x * 4 + wave) * 16;
    if (tilebase >= N) return;          // wave-uniform

    // ---- W frags (bf16, registers, once per wave; L2-hot) ----
    bf16x8 w1f[4];
    bf16x8 w2f[4][2];
#pragma unroll
    for (int t = 0; t < 4; t++) {
#pragma unroll
        for (int j = 0; j < 8; j++) {
            int k = quad * 8 + j;
            w1f[t][j] = (short)bf1(W1[k * 64 + t * 16 + n16]);
            w2f[t][0][j] = (short)bf1(W2[k * 64 + t * 16 + n16]);
            w2f[t][1][j] = (short)bf1(W2[(32 + k) * 64 + t * 16 + n16]);
        }
    }
    float b1v[4];
#pragma unroll
    for (int t = 0; t < 4; t++) b1v[t] = b1[t * 16 + n16];

    // ---- layer 1: one MFMA per col-tile (K=32 in one shot) ----
    int arow = min(tilebase + n16, N - 1);
    bf16x8 a1 = *reinterpret_cast<const bf16x8*>(h + (size_t)arow * 32 + quad * 8);
    f32x4 zero = {0.f, 0.f, 0.f, 0.f};
    f32x4 c[4];
#pragma unroll
    for (int t = 0; t < 4; t++)
        c[t] = __builtin_amdgcn_mfma_f32_16x16x32_bf16(a1, w1f[t], zero, 0, 0, 0);

    // bias + relu, pack C-layout -> LDS tile (wave-private)
#pragma unroll
    for (int t = 0; t < 4; t++)
#pragma unroll
        for (int i = 0; i < 4; i++)
            tile[quad * 4 + i][t * 16 + n16] = bf1(fmaxf(c[t][i] + b1v[t], 0.f));

    // ---- layer 2: reload u in A-layout, 2 K-chunks ----
    bf16x8 a2_0 = *reinterpret_cast<const bf16x8*>(&tile[n16][quad * 8]);
    bf16x8 a2_1 = *reinterpret_cast<const bf16x8*>(&tile[n16][32 + quad * 8]);
    f32x4 d[4];
#pragma unroll
    for (int t = 0; t < 4; t++) {
        d[t] = __builtin_amdgcn_mfma_f32_16x16x32_bf16(a2_0, w2f[t][0], zero, 0, 0, 0);
        d[t] = __builtin_amdgcn_mfma_f32_16x16x32_bf16(a2_1, w2f[t][1], d[t], 0, 0, 0);
    }

    // pack v to LDS, then coalesced bf16 store (16 rows x 64 = 2 KB)
#pragma unroll
    for (int t = 0; t < 4; t++)
#pragma unroll
        for (int i = 0; i < 4; i++)
            tile[quad * 4 + i][t * 16 + n16] = bf1(d[t][i]);

#pragma unroll
    for (int half = 0; half < 2; half++) {
        int g = half * 512 + lane * 8;
        int r = g >> 6, cc = g & 63;
        int grow = tilebase + r;
        if (grow < N)
            *reinterpret_cast<uint4*>(outb + (size_t)grow * 64 + cc) =
                *reinterpret_cast<const uint4*>(&tile[r][cc]);
    }
}

extern "C" void kernel_launch(void* const* d_in, const int* in_sizes, int n_in,
                              void* d_out, int out_size, void* d_ws, size_t ws_size,
                              hipStream_t stream) {
    const float* x        = (const float*)d_in[0];
    const float* edge_val = (const float*)d_in[1];
    const int*   edge_row = (const int*)d_in[2];
    const int*   edge_col = (const int*)d_in[3];
    const float* W1       = (const float*)d_in[4];
    const float* b1       = (const float*)d_in[5];
    const float* W2       = (const float*)d_in[6];
    const float* b2       = (const float*)d_in[7];
    float* out = (float*)d_out;

    const int N = in_sizes[0] / 32;   // 100000
    const int E = in_sizes[1];        // 1600000
    const int NREG = (N + REGION_SIZE - 1) >> REGION_SHIFT;  // 196

    // --- d_out as raw scratch (fp32 final write overwrites all) ---
    u16* xb  = (u16*)d_out;                    // N*32 bf16
    u16* t0b = xb + (size_t)N * 32;            // N*32 bf16
    u16* t2b = (u16*)d_out + (size_t)N * 64;   // N*64 bf16 (bytes [12.8,25.6MB))

    // --- ws layout ---
    u16*  wsb = (u16*)d_ws;                    // N*64 bf16: t1b then t3b
    int2* stg = (int2*)d_ws;                   // E int2 overlay (build only)
    int*  row_ptr    = (int*)((char*)d_ws + (size_t)N * 64 * 2);  // N+1
    int*  region_off = row_ptr + (N + 1);      // NREG+1
    int*  partial    = region_off + (NREG + 1);// GBUILD*256
    size_t cvOff = (size_t)((char*)(partial + GBUILD * 256) - (char*)d_ws);
    cvOff = (cvOff + 7) & ~(size_t)7;
    int2* cv = (int2*)((char*)d_ws + cvOff);   // E packed edges
    u16* t1b = wsb;
    u16* t3b = wsb;

    // ---- CSR build (2-pass radix, zero global atomics, no memset) ----
    region_count_kernel<<<GBUILD, 256, 0, stream>>>(edge_row, E, partial);
    region_scan_kernel<<<1, 256, 0, stream>>>(partial, region_off, NREG, E, GBUILD);
    region_base_kernel<<<NREG, 256, 0, stream>>>(partial, region_off, NREG);
    coarse_scatter_kernel<<<GBUILD, 256, 0, stream>>>(edge_row, edge_col, edge_val,
                                                      E, partial, stg);
    region_sort_kernel<<<NREG, 256, 0, stream>>>(stg, region_off, row_ptr, cv, N, E);

    // ---- pipeline ----
    int n4 = (N * 32) / 4;
    f32_to_bf16_kernel<<<(n4 + 255) / 256, 256, 0, stream>>>(x, xb, n4);

    int g32 = (N * 4 + 255) / 256;   // D=32: 4 lanes/row
    int g64 = (N * 8 + 255) / 256;   // D=64: 8 lanes/row

    spmm_bf16_kernel<32, false><<<g32, 256, 0, stream>>>(xb, row_ptr, cv, t0b, nullptr, N);
    spmm_bf16_kernel<32, false><<<g32, 256, 0, stream>>>(t0b, row_ptr, cv, t1b, nullptr, N);
    dense_mfma_kernel<<<(N + 63) / 64, 256, 0, stream>>>(t1b, W1, b1, W2, t2b, N);
    spmm_bf16_kernel<64, false><<<g64, 256, 0, stream>>>(t2b, row_ptr, cv, t3b, nullptr, N);
    spmm_bf16_kernel<64, true><<<g64, 256, 0, stream>>>(t3b, row_ptr, cv, out, b2, N);
}